// Round 1
// baseline (1367.249 us; speedup 1.0000x reference)
//
#include <hip/hip_runtime.h>

typedef short short8 __attribute__((ext_vector_type(8)));
typedef float f32x16 __attribute__((ext_vector_type(16)));

// Problem constants
#define DIMV   64
#define NEMB   1024
#define NROWS  262144          // B*T = 2048*128
#define DECAYF 0.99f
#define OMDF   0.01f
#define EPSF   1e-5f
#define BCAPMX 512             // max rows bucketed per code (overflow -> direct atomics)

// d_out layout (floats): quantize | loss | new_embed | new_cluster_size | new_embed_avg
#define OQ   0
#define OL   16777216
#define OE   16777217
#define ONC  16842753
#define OA   16843777
// EH/EL (bf16 split codebook, MFMA-B-fragment order) live in the d_out tail:
// written by vq_prep_b, read by vq_main, then overwritten by finalA/finalB.
#define OEH  16777216
#define OEL  (16777216 + 32768)

// d_ws layout (floats)
#define WS_E2     0        // 1024: ||e_k||^2
#define WS_CNT    1024     // 1024: counts (doubles as bucket cursor)
#define WS_ESUM   2048     // 65536: embed_sum, K-MAJOR: [k][d]
#define WS_LOSS   67584    // 1
#define WS_TOTAL  67585    // 1
#define WS_ET     67588    // 65536: embed transposed [k][d] fp32
#define WS_BUCKET 133124   // NEMB*cap ints: row-id buckets per code

// RNE float->bf16 (no NaN in data), and back
__device__ __forceinline__ unsigned short f2bf(float f) {
    unsigned u = __float_as_uint(f);
    u = u + 0x7FFFu + ((u >> 16) & 1u);
    return (unsigned short)(u >> 16);
}
__device__ __forceinline__ float bf2f(unsigned short h) {
    return __uint_as_float(((unsigned)h) << 16);
}

// ---------------------------------------------------------------- prep: transpose embed -> et[k][d]
__global__ void vq_prep(const float* __restrict__ embed, float* __restrict__ et)
{
    int idx = blockIdx.x * 256 + threadIdx.x;   // < 65536, idx = d*1024 + k
    int d = idx >> 10;
    int k = idx & (NEMB - 1);
    et[k * DIMV + d] = embed[idx];
}

__global__ void vq_e2(const float* __restrict__ et, float* __restrict__ e2)
{
    int k = blockIdx.x * 256 + threadIdx.x;   // k < 1024
    const float4* ep = (const float4*)(et + k * DIMV);
    float s = 0.f;
    #pragma unroll
    for (int i = 0; i < 16; i++) {
        float4 v = ep[i];
        s = fmaf(v.x, v.x, fmaf(v.y, v.y, fmaf(v.z, v.z, fmaf(v.w, v.w, s))));
    }
    e2[k] = s;
}

// ---------------------------------------------------------------- prep: split codebook into bf16 hi/lo,
// pre-swizzled into 32x32x16 MFMA B-fragment order:
// frag(nt,s): lane L, elem j  <->  B[k = s*16 + (L>>5)*8 + j][n = nt*32 + (L&31)]
__global__ void vq_prep_b(const float* __restrict__ embed,
                          unsigned short* __restrict__ eh,
                          unsigned short* __restrict__ el)
{
    int t = blockIdx.x * 256 + threadIdx.x;    // 0..65535
    int j  = t & 7;
    int L  = (t >> 3) & 63;
    int s  = (t >> 9) & 3;
    int nt = t >> 11;                          // 0..31
    int d    = s * 16 + (L >> 5) * 8 + j;
    int code = nt * 32 + (L & 31);
    float e = embed[d * NEMB + code];
    unsigned short hb = f2bf(e);
    eh[t] = hb;
    el[t] = f2bf(e - bf2f(hb));
}

// ---------------------------------------------------------------- main
__global__ __launch_bounds__(256, 2) void vq_main(
    const float* __restrict__ x, const int* __restrict__ mask,
    const unsigned short* __restrict__ eh, const unsigned short* __restrict__ el,
    const float* __restrict__ et, const float* __restrict__ e2g,
    float* __restrict__ out, float* __restrict__ counts,
    float* __restrict__ esum, float* __restrict__ lossacc,
    int* __restrict__ bucket, int cap)
{
    const int tid  = threadIdx.x;
    const int lane = tid & 63;
    const int wid  = tid >> 6;
    const int wbase = blockIdx.x * 256 + wid * 64;   // wave's first row
    const int lm = lane & 31;    // m (A) / n (B) within tile
    const int lh = lane >> 5;    // k-half selector

    // ---- A fragments: xh/xl for 2 M-tiles x 4 K-steps. A[m=lane&31][k=(lane>>5)*8+j]
    short8 ah[2][4], al[2][4];
    #pragma unroll
    for (int mt = 0; mt < 2; mt++) {
        const float* xr = x + (size_t)(wbase + mt * 32 + lm) * DIMV + lh * 8;
        #pragma unroll
        for (int s = 0; s < 4; s++) {
            const float* xp = xr + s * 16;
            #pragma unroll
            for (int j = 0; j < 8; j++) {
                float f = xp[j];
                unsigned short hb = f2bf(f);
                ah[mt][s][j] = (short)hb;
                al[mt][s][j] = (short)f2bf(f - bf2f(hb));
            }
        }
    }

    // per-lane top-2 keys per (mtile, acc-reg); key = (q<<10)|k, q = trunc(2048*(e2-2dot))
    int b1[2][16], b2[2][16];
    #pragma unroll
    for (int mt = 0; mt < 2; mt++)
        #pragma unroll
        for (int r = 0; r < 16; r++) { b1[mt][r] = 0x7FFFFFFF; b2[mt][r] = 0x7FFFFFFF; }

    const short8* ehf = (const short8*)eh;
    const short8* elf = (const short8*)el;

    for (int nt = 0; nt < 32; nt++) {
        short8 bh[4], bl[4];
        #pragma unroll
        for (int s = 0; s < 4; s++) {
            bh[s] = ehf[(nt * 4 + s) * 64 + lane];
            bl[s] = elf[(nt * 4 + s) * 64 + lane];
        }
        const int   klane = nt * 32 + lm;
        const float e2s   = e2g[klane] * 2048.0f;

        f32x16 acc0, acc1;
        #pragma unroll
        for (int i = 0; i < 16; i++) { acc0[i] = 0.0f; acc1[i] = 0.0f; }

        #pragma unroll
        for (int s = 0; s < 4; s++) {   // pass hh
            acc0 = __builtin_amdgcn_mfma_f32_32x32x16_bf16(ah[0][s], bh[s], acc0, 0, 0, 0);
            acc1 = __builtin_amdgcn_mfma_f32_32x32x16_bf16(ah[1][s], bh[s], acc1, 0, 0, 0);
        }
        #pragma unroll
        for (int s = 0; s < 4; s++) {   // pass hl
            acc0 = __builtin_amdgcn_mfma_f32_32x32x16_bf16(ah[0][s], bl[s], acc0, 0, 0, 0);
            acc1 = __builtin_amdgcn_mfma_f32_32x32x16_bf16(ah[1][s], bl[s], acc1, 0, 0, 0);
        }
        #pragma unroll
        for (int s = 0; s < 4; s++) {   // pass lh
            acc0 = __builtin_amdgcn_mfma_f32_32x32x16_bf16(al[0][s], bh[s], acc0, 0, 0, 0);
            acc1 = __builtin_amdgcn_mfma_f32_32x32x16_bf16(al[1][s], bh[s], acc1, 0, 0, 0);
        }

        #pragma unroll
        for (int r = 0; r < 16; r++) {
            int q0   = (int)fmaf(acc0[r], -4096.0f, e2s);     // 2048*(e2-2dot), trunc
            int key0 = (int)(((unsigned)q0) << 10) | klane;
            int lo0 = min(b1[0][r], key0), hi0 = max(b1[0][r], key0);
            b1[0][r] = lo0; b2[0][r] = min(b2[0][r], hi0);

            int q1   = (int)fmaf(acc1[r], -4096.0f, e2s);
            int key1 = (int)(((unsigned)q1) << 10) | klane;
            int lo1 = min(b1[1][r], key1), hi1 = max(b1[1][r], key1);
            b1[1][r] = lo1; b2[1][r] = min(b2[1][r], hi1);
        }
    }

    // ---- cross-lane reduction (per half-wave = 32 lanes sharing a row) ----
    int sm1 = 0x7FFFFFFF, sm2 = 0x7FFFFFFF, sc = 1;
    unsigned long long hm = (lane < 32) ? 0xFFFFFFFFull : 0xFFFFFFFF00000000ull;
    #pragma unroll
    for (int mt = 0; mt < 2; mt++) {
        #pragma unroll
        for (int r = 0; r < 16; r++) {
            int v1 = b1[mt][r], v2 = b2[mt][r];
            #pragma unroll
            for (int m = 1; m <= 16; m <<= 1) {
                int o1 = __shfl_xor(v1, m, 64);
                int o2 = __shfl_xor(v2, m, 64);
                int lo = min(v1, o1), hi = max(v1, o1);
                v1 = lo;
                v2 = min(min(v2, o2), hi);
            }
            int thr = (v1 >> 10) + 41;   // window = 41/2048 ~= 0.02
            bool in1 = (b1[mt][r] >> 10) <= thr;
            bool in2 = (b2[mt][r] >> 10) <= thr;
            unsigned long long B1 = __ballot(in1), B2 = __ballot(in2);
            int cnt = (int)__popcll(B1 & hm) + (int)__popcll(B2 & hm);
            int w1a = __shfl(v1, 0, 64),  w2a = __shfl(v2, 0, 64),  ca = __shfl(cnt, 0, 64);
            int w1b = __shfl(v1, 32, 64), w2b = __shfl(v2, 32, 64), cb = __shfl(cnt, 32, 64);
            int r0 = mt * 32 + (r & 3) + 8 * (r >> 2);
            if (lane == r0)     { sm1 = w1a; sm2 = w2a; sc = ca; }
            if (lane == r0 + 4) { sm1 = w1b; sm2 = w2b; sc = cb; }
        }
    }

    // ---- per-lane epilogue: lane owns row wbase+lane ----
    const int row = wbase + lane;
    int kw = sm1 & 1023;

    // ---- wave-cooperative exact full scan for sc>=3 rows (rare path).
    // Old per-lane 1024-iteration scan was a ~200+ us straggler pole; here all
    // 64 lanes split the codebook (16 codes/lane) -> ~64x less serial depth.
    {
        unsigned long long fm = __ballot(sc >= 3);
        while (fm) {
            int j = __ffsll(fm) - 1; fm &= (fm - 1);
            const float4* xr = (const float4*)(x + (size_t)(wbase + j) * DIMV);
            float4 xb[16];
            float xb2 = 0.f;
            #pragma unroll
            for (int i = 0; i < 16; i++) {
                float4 v = xr[i];                 // broadcast load (same addr all lanes)
                xb[i] = v;
                xb2 += v.x * v.x + v.y * v.y + v.z * v.z + v.w * v.w;
            }
            float bd = 3.4e38f; int bc = 0;
            for (int t = 0; t < 16; t++) {
                int c = lane + (t << 6);
                const float4* ep = (const float4*)(et + (c << 6));
                float ax = 0.f, ay = 0.f, az = 0.f, aw = 0.f;
                #pragma unroll 4
                for (int i = 0; i < 16; i++) {
                    float4 ev = ep[i];
                    ax = fmaf(xb[i].x, ev.x, ax);
                    ay = fmaf(xb[i].y, ev.y, ay);
                    az = fmaf(xb[i].z, ev.z, az);
                    aw = fmaf(xb[i].w, ev.w, aw);
                }
                float dot = (ax + ay) + (az + aw);
                float d = (xb2 - 2.0f * dot) + e2g[c];
                if (d < bd) { bd = d; bc = c; }   // ascending c: lowest idx on ties
            }
            #pragma unroll
            for (int m = 1; m < 64; m <<= 1) {    // lexicographic (dist, idx) min
                float od = __shfl_xor(bd, m, 64);
                int   oc = __shfl_xor(bc, m, 64);
                if (od < bd || (od == bd && oc < bc)) { bd = od; bc = oc; }
            }
            if (lane == j) kw = bc;
        }
    }

    float4 xv[16];
    {
        const float4* xp = (const float4*)(x + (size_t)row * DIMV);
        #pragma unroll
        for (int i = 0; i < 16; i++) xv[i] = xp[i];
    }

    if (sc == 2) {
        // exact recheck of the two candidates
        float x2 = 0.f;
        #pragma unroll
        for (int i = 0; i < 16; i++)
            x2 += xv[i].x * xv[i].x + xv[i].y * xv[i].y + xv[i].z * xv[i].z + xv[i].w * xv[i].w;

        auto fdist = [&](int k) -> float {
            const float4* ep = (const float4*)(et + (k << 6));
            float ax = 0.f, ay = 0.f, az = 0.f, aw = 0.f;
            #pragma unroll
            for (int i = 0; i < 16; i++) {
                float4 ev = ep[i];
                ax = fmaf(xv[i].x, ev.x, ax);
                ay = fmaf(xv[i].y, ev.y, ay);
                az = fmaf(xv[i].z, ev.z, az);
                aw = fmaf(xv[i].w, ev.w, aw);
            }
            float dot = (ax + ay) + (az + aw);
            return (x2 - 2.0f * dot) + e2g[k];
        };

        int k2 = sm2 & 1023;
        float d1 = fdist(kw);
        float d2 = fdist(k2);
        if (d2 < d1 || (d2 == d1 && k2 < kw)) kw = k2;
    }

    const bool valid = (mask[row] == 0);   // valid = ~mask
    float sq = 0.f;
    float4* qp = (float4*)(out + OQ + (size_t)row * DIMV);
    const float4* erow = (const float4*)(et + (kw << 6));
    #pragma unroll
    for (int i = 0; i < 16; i++) {
        float4 xvv = xv[i];
        float4 ev  = erow[i];
        float q0 = xvv.x + (ev.x - xvv.x);
        float q1 = xvv.y + (ev.y - xvv.y);
        float q2 = xvv.z + (ev.z - xvv.z);
        float q3 = xvv.w + (ev.w - xvv.w);
        float4 q4 = {q0, q1, q2, q3};
        qp[i] = q4;
        float d0 = q0 - xvv.x, d1 = q1 - xvv.y, d2 = q2 - xvv.z, d3 = q3 - xvv.w;
        sq += d0 * d0 + d1 * d1 + d2 * d2 + d3 * d3;
    }

    // ---- bucketed EMA scatter: counts-atomic doubles as bucket cursor.
    // 1 dword store per valid row instead of 64 dword device-atomics
    // (removes ~8.4M memory-side RMWs = the 33.6 MB WRITE_SIZE excess).
    if (valid) {
        int pos = (int)atomicAdd(&counts[kw], 1.0f);
        if (pos < cap) {
            bucket[kw * cap + pos] = row;
        } else {
            // overflow fallback (arbitrary-data correctness; never hit for random data)
            float* ep = esum + (kw << 6);
            #pragma unroll
            for (int i = 0; i < 16; i++) {
                atomicAdd(ep + 4 * i + 0, xv[i].x);
                atomicAdd(ep + 4 * i + 1, xv[i].y);
                atomicAdd(ep + 4 * i + 2, xv[i].z);
                atomicAdd(ep + 4 * i + 3, xv[i].w);
            }
        }
    }

    float v = valid ? sq : 0.0f;
    #pragma unroll
    for (int off = 32; off > 0; off >>= 1) v += __shfl_down(v, off, 64);
    if (lane == 0) atomicAdd(lossacc, v);
}

// ---------------------------------------------------------------- pass 2: per-code bucket sum
// block c owns code c exclusively: coalesced x reads, ONE plain write per (code,dim).
__global__ __launch_bounds__(64) void vq_esum(
    const float* __restrict__ x, const float* __restrict__ counts,
    const int* __restrict__ bucket, float* __restrict__ esum, int cap)
{
    const int c = blockIdx.x;
    const int d = threadIdx.x;
    int n = (int)counts[c];
    if (n > cap) n = cap;
    const int* bp = bucket + c * cap;
    float a0 = 0.f, a1 = 0.f, a2 = 0.f, a3 = 0.f;
    int i = 0;
    for (; i + 8 <= n; i += 8) {
        int r0 = bp[i],     r1 = bp[i + 1], r2 = bp[i + 2], r3 = bp[i + 3];
        int r4 = bp[i + 4], r5 = bp[i + 5], r6 = bp[i + 6], r7 = bp[i + 7];
        a0 += x[(size_t)r0 * DIMV + d];
        a1 += x[(size_t)r1 * DIMV + d];
        a2 += x[(size_t)r2 * DIMV + d];
        a3 += x[(size_t)r3 * DIMV + d];
        a0 += x[(size_t)r4 * DIMV + d];
        a1 += x[(size_t)r5 * DIMV + d];
        a2 += x[(size_t)r6 * DIMV + d];
        a3 += x[(size_t)r7 * DIMV + d];
    }
    for (; i < n; i++) a0 += x[(size_t)bp[i] * DIMV + d];
    // += keeps overflow-path direct-atomic contributions (esum zeroed per launch)
    esum[(c << 6) + d] += (a0 + a1) + (a2 + a3);
}

// ---------------------------------------------------------------- finalize A
__global__ __launch_bounds__(1024) void vq_finalA(
    const float* __restrict__ cluster_size, const float* __restrict__ counts,
    const float* __restrict__ lossacc, float* __restrict__ out,
    float* __restrict__ total_ws)
{
    __shared__ float s1[1024];
    __shared__ float s2[1024];
    int k = threadIdx.x;
    float c   = counts[k];
    float ncs = cluster_size[k] * DECAYF + OMDF * c;
    out[ONC + k] = ncs;
    s1[k] = ncs; s2[k] = c;
    __syncthreads();
    for (int off = 512; off > 0; off >>= 1) {
        if (k < off) { s1[k] += s1[k + off]; s2[k] += s2[k + off]; }
        __syncthreads();
    }
    if (k == 0) {
        total_ws[0] = s1[0];
        out[OL] = lossacc[0] / (s2[0] * (float)DIMV);
    }
}

// ---------------------------------------------------------------- finalize B (esum is k-major now)
__global__ void vq_finalB(const float* __restrict__ embed_avg,
                          const float* __restrict__ esum,
                          float* __restrict__ out,
                          const float* __restrict__ total_ws)
{
    int idx = blockIdx.x * 256 + threadIdx.x;  // < 65536, idx = d*1024 + k
    int k = idx & (NEMB - 1);
    int d = idx >> 10;
    float avg = embed_avg[idx] * DECAYF + OMDF * esum[(k << 6) + d];
    out[OA + idx] = avg;
    float ncs   = out[ONC + k];
    float total = *total_ws;
    float sm = (ncs + EPSF) / (total + (float)NEMB * EPSF) * total;
    out[OE + idx] = avg / sm;
}

// ---------------------------------------------------------------- launcher
extern "C" void kernel_launch(void* const* d_in, const int* in_sizes, int n_in,
                              void* d_out, int out_size, void* d_ws, size_t ws_size,
                              hipStream_t stream)
{
    const float* x            = (const float*)d_in[0];
    const int*   mask         = (const int*)d_in[1];
    const float* embed        = (const float*)d_in[2];
    const float* cluster_size = (const float*)d_in[3];
    const float* embed_avg    = (const float*)d_in[4];
    float* out = (float*)d_out;
    float* ws  = (float*)d_ws;

    unsigned short* eh = (unsigned short*)(out + OEH);
    unsigned short* el = (unsigned short*)(out + OEL);

    // bucket capacity from available workspace (cap==0 -> pure atomic fallback, still correct)
    int cap = 0;
    size_t avail = ws_size / sizeof(float);
    if (avail > (size_t)WS_BUCKET) {
        size_t per = (avail - (size_t)WS_BUCKET) / (size_t)NEMB;
        cap = per > (size_t)BCAPMX ? BCAPMX : (int)per;
    }
    int* bucket = (int*)(ws + WS_BUCKET);

    // zero accumulators (counts, esum, loss, total)
    hipMemsetAsync(ws + WS_CNT, 0, (size_t)(WS_TOTAL + 1 - WS_CNT) * sizeof(float), stream);

    vq_prep<<<65536 / 256, 256, 0, stream>>>(embed, ws + WS_ET);
    vq_e2<<<NEMB / 256, 256, 0, stream>>>(ws + WS_ET, ws + WS_E2);
    vq_prep_b<<<65536 / 256, 256, 0, stream>>>(embed, eh, el);
    vq_main<<<NROWS / 256, 256, 0, stream>>>(x, mask, eh, el, ws + WS_ET, ws + WS_E2,
                                             out, ws + WS_CNT, ws + WS_ESUM, ws + WS_LOSS,
                                             bucket, cap);
    vq_esum<<<NEMB, 64, 0, stream>>>(x, ws + WS_CNT, bucket, ws + WS_ESUM, cap);
    vq_finalA<<<1, 1024, 0, stream>>>(cluster_size, ws + WS_CNT, ws + WS_LOSS,
                                      out, ws + WS_TOTAL);
    vq_finalB<<<65536 / 256, 256, 0, stream>>>(embed_avg, ws + WS_ESUM, out, ws + WS_TOTAL);
}

// Round 2
// 1334.670 us; speedup vs baseline: 1.0244x; 1.0244x over previous
//
#include <hip/hip_runtime.h>

typedef short short8 __attribute__((ext_vector_type(8)));
typedef float f32x16 __attribute__((ext_vector_type(16)));

// Problem constants
#define DIMV   64
#define NEMB   1024
#define NROWS  262144          // B*T = 2048*128
#define DECAYF 0.99f
#define OMDF   0.01f
#define EPSF   1e-5f

// d_out layout (floats): quantize | loss | new_embed | new_cluster_size | new_embed_avg
#define OQ   0
#define OL   16777216
#define OE   16777217
#define ONC  16842753
#define OA   16843777
// EH/EL (bf16 split codebook, MFMA-B-fragment order) live in the d_out tail:
// written by vq_prep_b, read by vq_main, then overwritten by finalA/finalB.
#define OEH  16777216
#define OEL  (16777216 + 32768)

// d_ws layout (floats)
#define WS_E2     0        // 1024: ||e_k||^2
#define WS_CNT    1024     // 1024: counts (plain stores from vq_gather)
#define WS_ESUM   2048     // 65536: embed_sum, K-MAJOR: [k][d]
#define WS_LOSS   67584    // 1
#define WS_TOTAL  67585    // 1
#define WS_ET     67588    // 65536: embed transposed [k][d] fp32
#define WS_KWV    133124   // 131072 floats = 262144 ushorts: per-row code (0xFFFF = masked)

// RNE float->bf16 (no NaN in data), and back
__device__ __forceinline__ unsigned short f2bf(float f) {
    unsigned u = __float_as_uint(f);
    u = u + 0x7FFFu + ((u >> 16) & 1u);
    return (unsigned short)(u >> 16);
}
__device__ __forceinline__ float bf2f(unsigned short h) {
    return __uint_as_float(((unsigned)h) << 16);
}

// ---------------------------------------------------------------- prep: transpose embed -> et[k][d]
__global__ void vq_prep(const float* __restrict__ embed, float* __restrict__ et)
{
    int idx = blockIdx.x * 256 + threadIdx.x;   // < 65536, idx = d*1024 + k
    int d = idx >> 10;
    int k = idx & (NEMB - 1);
    et[k * DIMV + d] = embed[idx];
}

__global__ void vq_e2(const float* __restrict__ et, float* __restrict__ e2)
{
    int k = blockIdx.x * 256 + threadIdx.x;   // k < 1024
    const float4* ep = (const float4*)(et + k * DIMV);
    float s = 0.f;
    #pragma unroll
    for (int i = 0; i < 16; i++) {
        float4 v = ep[i];
        s = fmaf(v.x, v.x, fmaf(v.y, v.y, fmaf(v.z, v.z, fmaf(v.w, v.w, s))));
    }
    e2[k] = s;
}

// ---------------------------------------------------------------- prep: split codebook into bf16 hi/lo,
// pre-swizzled into 32x32x16 MFMA B-fragment order:
// frag(nt,s): lane L, elem j  <->  B[k = s*16 + (L>>5)*8 + j][n = nt*32 + (L&31)]
__global__ void vq_prep_b(const float* __restrict__ embed,
                          unsigned short* __restrict__ eh,
                          unsigned short* __restrict__ el)
{
    int t = blockIdx.x * 256 + threadIdx.x;    // 0..65535
    int j  = t & 7;
    int L  = (t >> 3) & 63;
    int s  = (t >> 9) & 3;
    int nt = t >> 11;                          // 0..31
    int d    = s * 16 + (L >> 5) * 8 + j;
    int code = nt * 32 + (L & 31);
    float e = embed[d * NEMB + code];
    unsigned short hb = f2bf(e);
    eh[t] = hb;
    el[t] = f2bf(e - bf2f(hb));
}

// ---------------------------------------------------------------- main
// No device atomics except ONE per-wave loss add. EMA inputs (counts/esum)
// are derived from kwv[] by vq_gather, so waves retire without an atomic drain.
__global__ __launch_bounds__(256, 2) void vq_main(
    const float* __restrict__ x, const int* __restrict__ mask,
    const unsigned short* __restrict__ eh, const unsigned short* __restrict__ el,
    const float* __restrict__ et, const float* __restrict__ e2g,
    float* __restrict__ out, unsigned short* __restrict__ kwv,
    float* __restrict__ lossacc)
{
    const int tid  = threadIdx.x;
    const int lane = tid & 63;
    const int wid  = tid >> 6;
    const int wbase = blockIdx.x * 256 + wid * 64;   // wave's first row
    const int lm = lane & 31;    // m (A) / n (B) within tile
    const int lh = lane >> 5;    // k-half selector

    // ---- A fragments: xh/xl for 2 M-tiles x 4 K-steps. A[m=lane&31][k=(lane>>5)*8+j]
    short8 ah[2][4], al[2][4];
    #pragma unroll
    for (int mt = 0; mt < 2; mt++) {
        const float* xr = x + (size_t)(wbase + mt * 32 + lm) * DIMV + lh * 8;
        #pragma unroll
        for (int s = 0; s < 4; s++) {
            const float* xp = xr + s * 16;
            #pragma unroll
            for (int j = 0; j < 8; j++) {
                float f = xp[j];
                unsigned short hb = f2bf(f);
                ah[mt][s][j] = (short)hb;
                al[mt][s][j] = (short)f2bf(f - bf2f(hb));
            }
        }
    }

    // per-lane top-2 keys per (mtile, acc-reg); key = (q<<10)|k, q = trunc(2048*(e2-2dot))
    int b1[2][16], b2[2][16];
    #pragma unroll
    for (int mt = 0; mt < 2; mt++)
        #pragma unroll
        for (int r = 0; r < 16; r++) { b1[mt][r] = 0x7FFFFFFF; b2[mt][r] = 0x7FFFFFFF; }

    const short8* ehf = (const short8*)eh;
    const short8* elf = (const short8*)el;

    for (int nt = 0; nt < 32; nt++) {
        short8 bh[4], bl[4];
        #pragma unroll
        for (int s = 0; s < 4; s++) {
            bh[s] = ehf[(nt * 4 + s) * 64 + lane];
            bl[s] = elf[(nt * 4 + s) * 64 + lane];
        }
        const int   klane = nt * 32 + lm;
        const float e2s   = e2g[klane] * 2048.0f;

        f32x16 acc0, acc1;
        #pragma unroll
        for (int i = 0; i < 16; i++) { acc0[i] = 0.0f; acc1[i] = 0.0f; }

        #pragma unroll
        for (int s = 0; s < 4; s++) {   // pass hh
            acc0 = __builtin_amdgcn_mfma_f32_32x32x16_bf16(ah[0][s], bh[s], acc0, 0, 0, 0);
            acc1 = __builtin_amdgcn_mfma_f32_32x32x16_bf16(ah[1][s], bh[s], acc1, 0, 0, 0);
        }
        #pragma unroll
        for (int s = 0; s < 4; s++) {   // pass hl
            acc0 = __builtin_amdgcn_mfma_f32_32x32x16_bf16(ah[0][s], bl[s], acc0, 0, 0, 0);
            acc1 = __builtin_amdgcn_mfma_f32_32x32x16_bf16(ah[1][s], bl[s], acc1, 0, 0, 0);
        }
        #pragma unroll
        for (int s = 0; s < 4; s++) {   // pass lh
            acc0 = __builtin_amdgcn_mfma_f32_32x32x16_bf16(al[0][s], bh[s], acc0, 0, 0, 0);
            acc1 = __builtin_amdgcn_mfma_f32_32x32x16_bf16(al[1][s], bh[s], acc1, 0, 0, 0);
        }

        #pragma unroll
        for (int r = 0; r < 16; r++) {
            int q0   = (int)fmaf(acc0[r], -4096.0f, e2s);     // 2048*(e2-2dot), trunc
            int key0 = (int)(((unsigned)q0) << 10) | klane;
            int lo0 = min(b1[0][r], key0), hi0 = max(b1[0][r], key0);
            b1[0][r] = lo0; b2[0][r] = min(b2[0][r], hi0);

            int q1   = (int)fmaf(acc1[r], -4096.0f, e2s);
            int key1 = (int)(((unsigned)q1) << 10) | klane;
            int lo1 = min(b1[1][r], key1), hi1 = max(b1[1][r], key1);
            b1[1][r] = lo1; b2[1][r] = min(b2[1][r], hi1);
        }
    }

    // ---- cross-lane reduction (per half-wave = 32 lanes sharing a row) ----
    int sm1 = 0x7FFFFFFF, sm2 = 0x7FFFFFFF, sc = 1;
    unsigned long long hm = (lane < 32) ? 0xFFFFFFFFull : 0xFFFFFFFF00000000ull;
    #pragma unroll
    for (int mt = 0; mt < 2; mt++) {
        #pragma unroll
        for (int r = 0; r < 16; r++) {
            int v1 = b1[mt][r], v2 = b2[mt][r];
            #pragma unroll
            for (int m = 1; m <= 16; m <<= 1) {
                int o1 = __shfl_xor(v1, m, 64);
                int o2 = __shfl_xor(v2, m, 64);
                int lo = min(v1, o1), hi = max(v1, o1);
                v1 = lo;
                v2 = min(min(v2, o2), hi);
            }
            int thr = (v1 >> 10) + 41;   // window = 41/2048 ~= 0.02
            bool in1 = (b1[mt][r] >> 10) <= thr;
            bool in2 = (b2[mt][r] >> 10) <= thr;
            unsigned long long B1 = __ballot(in1), B2 = __ballot(in2);
            int cnt = (int)__popcll(B1 & hm) + (int)__popcll(B2 & hm);
            int w1a = __shfl(v1, 0, 64),  w2a = __shfl(v2, 0, 64),  ca = __shfl(cnt, 0, 64);
            int w1b = __shfl(v1, 32, 64), w2b = __shfl(v2, 32, 64), cb = __shfl(cnt, 32, 64);
            int r0 = mt * 32 + (r & 3) + 8 * (r >> 2);
            if (lane == r0)     { sm1 = w1a; sm2 = w2a; sc = ca; }
            if (lane == r0 + 4) { sm1 = w1b; sm2 = w2b; sc = cb; }
        }
    }

    // ---- per-lane epilogue: lane owns row wbase+lane ----
    const int row = wbase + lane;
    int kw = sm1 & 1023;

    // ---- wave-cooperative exact full scan for sc>=3 rows (rare path).
    // All 64 lanes split the codebook (16 codes/lane) -> ~64x less serial depth
    // than a per-lane 1024-iteration scan.
    {
        unsigned long long fm = __ballot(sc >= 3);
        while (fm) {
            int j = __ffsll(fm) - 1; fm &= (fm - 1);
            const float4* xr = (const float4*)(x + (size_t)(wbase + j) * DIMV);
            float4 xb[16];
            float xb2 = 0.f;
            #pragma unroll
            for (int i = 0; i < 16; i++) {
                float4 v = xr[i];                 // broadcast load (same addr all lanes)
                xb[i] = v;
                xb2 += v.x * v.x + v.y * v.y + v.z * v.z + v.w * v.w;
            }
            float bd = 3.4e38f; int bc = 0;
            for (int t = 0; t < 16; t++) {
                int c = lane + (t << 6);
                const float4* ep = (const float4*)(et + (c << 6));
                float ax = 0.f, ay = 0.f, az = 0.f, aw = 0.f;
                #pragma unroll 4
                for (int i = 0; i < 16; i++) {
                    float4 ev = ep[i];
                    ax = fmaf(xb[i].x, ev.x, ax);
                    ay = fmaf(xb[i].y, ev.y, ay);
                    az = fmaf(xb[i].z, ev.z, az);
                    aw = fmaf(xb[i].w, ev.w, aw);
                }
                float dot = (ax + ay) + (az + aw);
                float d = (xb2 - 2.0f * dot) + e2g[c];
                if (d < bd) { bd = d; bc = c; }   // ascending c: lowest idx on ties
            }
            #pragma unroll
            for (int m = 1; m < 64; m <<= 1) {    // lexicographic (dist, idx) min
                float od = __shfl_xor(bd, m, 64);
                int   oc = __shfl_xor(bc, m, 64);
                if (od < bd || (od == bd && oc < bc)) { bd = od; bc = oc; }
            }
            if (lane == j) kw = bc;
        }
    }

    float4 xv[16];
    {
        const float4* xp = (const float4*)(x + (size_t)row * DIMV);
        #pragma unroll
        for (int i = 0; i < 16; i++) xv[i] = xp[i];
    }

    if (sc == 2) {
        // exact recheck of the two candidates
        float x2 = 0.f;
        #pragma unroll
        for (int i = 0; i < 16; i++)
            x2 += xv[i].x * xv[i].x + xv[i].y * xv[i].y + xv[i].z * xv[i].z + xv[i].w * xv[i].w;

        auto fdist = [&](int k) -> float {
            const float4* ep = (const float4*)(et + (k << 6));
            float ax = 0.f, ay = 0.f, az = 0.f, aw = 0.f;
            #pragma unroll
            for (int i = 0; i < 16; i++) {
                float4 ev = ep[i];
                ax = fmaf(xv[i].x, ev.x, ax);
                ay = fmaf(xv[i].y, ev.y, ay);
                az = fmaf(xv[i].z, ev.z, az);
                aw = fmaf(xv[i].w, ev.w, aw);
            }
            float dot = (ax + ay) + (az + aw);
            return (x2 - 2.0f * dot) + e2g[k];
        };

        int k2 = sm2 & 1023;
        float d1 = fdist(kw);
        float d2 = fdist(k2);
        if (d2 < d1 || (d2 == d1 && k2 < kw)) kw = k2;
    }

    const bool valid = (mask[row] == 0);   // valid = ~mask
    float sq = 0.f;
    float4* qp = (float4*)(out + OQ + (size_t)row * DIMV);
    const float4* erow = (const float4*)(et + (kw << 6));
    #pragma unroll
    for (int i = 0; i < 16; i++) {
        float4 xvv = xv[i];
        float4 ev  = erow[i];
        float q0 = xvv.x + (ev.x - xvv.x);
        float q1 = xvv.y + (ev.y - xvv.y);
        float q2 = xvv.z + (ev.z - xvv.z);
        float q3 = xvv.w + (ev.w - xvv.w);
        float4 q4 = {q0, q1, q2, q3};
        qp[i] = q4;
        float d0 = q0 - xvv.x, d1 = q1 - xvv.y, d2 = q2 - xvv.z, d3 = q3 - xvv.w;
        sq += d0 * d0 + d1 * d1 + d2 * d2 + d3 * d3;
    }

    // per-row code record: ONE plain coalesced 2B store, no atomics.
    kwv[row] = valid ? (unsigned short)kw : (unsigned short)0xFFFF;

    float v = valid ? sq : 0.0f;
    #pragma unroll
    for (int off = 32; off > 0; off >>= 1) v += __shfl_down(v, off, 64);
    if (lane == 0) atomicAdd(lossacc, v);
}

// ---------------------------------------------------------------- pass 2: per-code gather-sum
// Wave w of block b owns code c = b*4+w exclusively. Scans the 512 KB kwv array
// (L2-resident; each lane checks 8 entries/iter via one 16B load), ballots matches,
// and accumulates matching x rows with fully-coalesced 256B loads (d = lane).
// Plain stores for esum and counts — zero atomics.
__global__ __launch_bounds__(256) void vq_gather(
    const float* __restrict__ x, const unsigned short* __restrict__ kwv,
    float* __restrict__ esum, float* __restrict__ counts)
{
    const int lane = threadIdx.x & 63;
    const int c    = blockIdx.x * 4 + (threadIdx.x >> 6);

    const short8* kp = (const short8*)kwv;   // 8 ushorts per lane-load
    float acc = 0.f;
    int   cnt = 0;

    for (int it = 0; it < NROWS / 512; it++) {
        short8 v = kp[it * 64 + lane];
        int m0 = ((unsigned short)v[0] == c);
        int m1 = ((unsigned short)v[1] == c);
        int m2 = ((unsigned short)v[2] == c);
        int m3 = ((unsigned short)v[3] == c);
        int m4 = ((unsigned short)v[4] == c);
        int m5 = ((unsigned short)v[5] == c);
        int m6 = ((unsigned short)v[6] == c);
        int m7 = ((unsigned short)v[7] == c);
        int any = m0 | m1 | m2 | m3 | m4 | m5 | m6 | m7;
        if (__ballot(any != 0) == 0ull) continue;   // fast path: no match in this 512-row chunk

        #pragma unroll
        for (int j = 0; j < 8; j++) {
            int mj = (j == 0) ? m0 : (j == 1) ? m1 : (j == 2) ? m2 : (j == 3) ? m3
                   : (j == 4) ? m4 : (j == 5) ? m5 : (j == 6) ? m6 : m7;
            unsigned long long bm = __ballot(mj != 0);
            cnt += (int)__popcll(bm);
            while (bm) {
                int l = (int)__ffsll(bm) - 1; bm &= bm - 1;
                int row = it * 512 + l * 8 + j;
                acc += x[(size_t)row * DIMV + lane];   // coalesced: 64 lanes = 64 dims
            }
        }
    }

    esum[(c << 6) + lane] = acc;
    if (lane == 0) counts[c] = (float)cnt;
}

// ---------------------------------------------------------------- finalize A
__global__ __launch_bounds__(1024) void vq_finalA(
    const float* __restrict__ cluster_size, const float* __restrict__ counts,
    const float* __restrict__ lossacc, float* __restrict__ out,
    float* __restrict__ total_ws)
{
    __shared__ float s1[1024];
    __shared__ float s2[1024];
    int k = threadIdx.x;
    float c   = counts[k];
    float ncs = cluster_size[k] * DECAYF + OMDF * c;
    out[ONC + k] = ncs;
    s1[k] = ncs; s2[k] = c;
    __syncthreads();
    for (int off = 512; off > 0; off >>= 1) {
        if (k < off) { s1[k] += s1[k + off]; s2[k] += s2[k + off]; }
        __syncthreads();
    }
    if (k == 0) {
        total_ws[0] = s1[0];
        out[OL] = lossacc[0] / (s2[0] * (float)DIMV);
    }
}

// ---------------------------------------------------------------- finalize B (esum is k-major)
__global__ void vq_finalB(const float* __restrict__ embed_avg,
                          const float* __restrict__ esum,
                          float* __restrict__ out,
                          const float* __restrict__ total_ws)
{
    int idx = blockIdx.x * 256 + threadIdx.x;  // < 65536, idx = d*1024 + k
    int k = idx & (NEMB - 1);
    int d = idx >> 10;
    float avg = embed_avg[idx] * DECAYF + OMDF * esum[(k << 6) + d];
    out[OA + idx] = avg;
    float ncs   = out[ONC + k];
    float total = *total_ws;
    float sm = (ncs + EPSF) / (total + (float)NEMB * EPSF) * total;
    out[OE + idx] = avg / sm;
}

// ---------------------------------------------------------------- launcher
extern "C" void kernel_launch(void* const* d_in, const int* in_sizes, int n_in,
                              void* d_out, int out_size, void* d_ws, size_t ws_size,
                              hipStream_t stream)
{
    const float* x            = (const float*)d_in[0];
    const int*   mask         = (const int*)d_in[1];
    const float* embed        = (const float*)d_in[2];
    const float* cluster_size = (const float*)d_in[3];
    const float* embed_avg    = (const float*)d_in[4];
    float* out = (float*)d_out;
    float* ws  = (float*)d_ws;

    unsigned short* eh  = (unsigned short*)(out + OEH);
    unsigned short* el  = (unsigned short*)(out + OEL);
    unsigned short* kwv = (unsigned short*)(ws + WS_KWV);

    // zero loss + total only (esum/counts are plain-stored by vq_gather)
    hipMemsetAsync(ws + WS_LOSS, 0, 2 * sizeof(float), stream);

    vq_prep<<<65536 / 256, 256, 0, stream>>>(embed, ws + WS_ET);
    vq_e2<<<NEMB / 256, 256, 0, stream>>>(ws + WS_ET, ws + WS_E2);
    vq_prep_b<<<65536 / 256, 256, 0, stream>>>(embed, eh, el);
    vq_main<<<NROWS / 256, 256, 0, stream>>>(x, mask, eh, el, ws + WS_ET, ws + WS_E2,
                                             out, kwv, ws + WS_LOSS);
    vq_gather<<<NEMB / 4, 256, 0, stream>>>(x, kwv, ws + WS_ESUM, ws + WS_CNT);
    vq_finalA<<<1, 1024, 0, stream>>>(cluster_size, ws + WS_CNT, ws + WS_LOSS,
                                      out, ws + WS_TOTAL);
    vq_finalB<<<65536 / 256, 256, 0, stream>>>(embed_avg, ws + WS_ESUM, out, ws + WS_TOTAL);
}

// Round 3
// 496.850 us; speedup vs baseline: 2.7518x; 2.6863x over previous
//
#include <hip/hip_runtime.h>

typedef short short8 __attribute__((ext_vector_type(8)));
typedef float f32x16 __attribute__((ext_vector_type(16)));

// Problem constants
#define DIMV   64
#define NEMB   1024
#define NROWS  262144          // B*T = 2048*128
#define DECAYF 0.99f
#define OMDF   0.01f
#define EPSF   1e-5f
#define GCHUNK 16384           // rows per gather chunk (queue bound: 16 chunks)

// d_out layout (floats): quantize | loss | new_embed | new_cluster_size | new_embed_avg
#define OQ   0
#define OL   16777216
#define OE   16777217
#define ONC  16842753
#define OA   16843777
// EH/EL (bf16 split codebook, MFMA-B-fragment order) live in the d_out tail:
// written by vq_prep_b, read by vq_main, then overwritten by finalA/finalB.
#define OEH  16777216
#define OEL  (16777216 + 32768)

// d_ws layout (floats)
#define WS_E2     0        // 1024: ||e_k||^2
#define WS_CNT    1024     // 1024: counts (plain stores from vq_gather)
#define WS_ESUM   2048     // 65536: embed_sum, K-MAJOR: [k][d]
#define WS_LOSS   67584    // 1
#define WS_TOTAL  67585    // 1
#define WS_ET     67588    // 65536: embed transposed [k][d] fp32
#define WS_KWV    133124   // 131072 floats = 262144 ushorts: per-row code (0xFFFF = masked)

// RNE float->bf16 (no NaN in data), and back
__device__ __forceinline__ unsigned short f2bf(float f) {
    unsigned u = __float_as_uint(f);
    u = u + 0x7FFFu + ((u >> 16) & 1u);
    return (unsigned short)(u >> 16);
}
__device__ __forceinline__ float bf2f(unsigned short h) {
    return __uint_as_float(((unsigned)h) << 16);
}

// ---------------------------------------------------------------- prep: transpose embed -> et[k][d]
__global__ void vq_prep(const float* __restrict__ embed, float* __restrict__ et)
{
    int idx = blockIdx.x * 256 + threadIdx.x;   // < 65536, idx = d*1024 + k
    int d = idx >> 10;
    int k = idx & (NEMB - 1);
    et[k * DIMV + d] = embed[idx];
}

__global__ void vq_e2(const float* __restrict__ et, float* __restrict__ e2)
{
    int k = blockIdx.x * 256 + threadIdx.x;   // k < 1024
    const float4* ep = (const float4*)(et + k * DIMV);
    float s = 0.f;
    #pragma unroll
    for (int i = 0; i < 16; i++) {
        float4 v = ep[i];
        s = fmaf(v.x, v.x, fmaf(v.y, v.y, fmaf(v.z, v.z, fmaf(v.w, v.w, s))));
    }
    e2[k] = s;
}

// ---------------------------------------------------------------- prep: split codebook into bf16 hi/lo,
// pre-swizzled into 32x32x16 MFMA B-fragment order:
// frag(nt,s): lane L, elem j  <->  B[k = s*16 + (L>>5)*8 + j][n = nt*32 + (L&31)]
__global__ void vq_prep_b(const float* __restrict__ embed,
                          unsigned short* __restrict__ eh,
                          unsigned short* __restrict__ el)
{
    int t = blockIdx.x * 256 + threadIdx.x;    // 0..65535
    int j  = t & 7;
    int L  = (t >> 3) & 63;
    int s  = (t >> 9) & 3;
    int nt = t >> 11;                          // 0..31
    int d    = s * 16 + (L >> 5) * 8 + j;
    int code = nt * 32 + (L & 31);
    float e = embed[d * NEMB + code];
    unsigned short hb = f2bf(e);
    eh[t] = hb;
    el[t] = f2bf(e - bf2f(hb));
}

// ---------------------------------------------------------------- main
// No device atomics except ONE per-wave loss add. EMA inputs (counts/esum)
// are derived from kwv[] by vq_gather, so waves retire without an atomic drain.
__global__ __launch_bounds__(256, 2) void vq_main(
    const float* __restrict__ x, const int* __restrict__ mask,
    const unsigned short* __restrict__ eh, const unsigned short* __restrict__ el,
    const float* __restrict__ et, const float* __restrict__ e2g,
    float* __restrict__ out, unsigned short* __restrict__ kwv,
    float* __restrict__ lossacc)
{
    const int tid  = threadIdx.x;
    const int lane = tid & 63;
    const int wid  = tid >> 6;
    const int wbase = blockIdx.x * 256 + wid * 64;   // wave's first row
    const int lm = lane & 31;    // m (A) / n (B) within tile
    const int lh = lane >> 5;    // k-half selector

    // ---- A fragments: xh/xl for 2 M-tiles x 4 K-steps. A[m=lane&31][k=(lane>>5)*8+j]
    short8 ah[2][4], al[2][4];
    #pragma unroll
    for (int mt = 0; mt < 2; mt++) {
        const float* xr = x + (size_t)(wbase + mt * 32 + lm) * DIMV + lh * 8;
        #pragma unroll
        for (int s = 0; s < 4; s++) {
            const float* xp = xr + s * 16;
            #pragma unroll
            for (int j = 0; j < 8; j++) {
                float f = xp[j];
                unsigned short hb = f2bf(f);
                ah[mt][s][j] = (short)hb;
                al[mt][s][j] = (short)f2bf(f - bf2f(hb));
            }
        }
    }

    // per-lane top-2 keys per (mtile, acc-reg); key = (q<<10)|k, q = trunc(2048*(e2-2dot))
    int b1[2][16], b2[2][16];
    #pragma unroll
    for (int mt = 0; mt < 2; mt++)
        #pragma unroll
        for (int r = 0; r < 16; r++) { b1[mt][r] = 0x7FFFFFFF; b2[mt][r] = 0x7FFFFFFF; }

    const short8* ehf = (const short8*)eh;
    const short8* elf = (const short8*)el;

    for (int nt = 0; nt < 32; nt++) {
        short8 bh[4], bl[4];
        #pragma unroll
        for (int s = 0; s < 4; s++) {
            bh[s] = ehf[(nt * 4 + s) * 64 + lane];
            bl[s] = elf[(nt * 4 + s) * 64 + lane];
        }
        const int   klane = nt * 32 + lm;
        const float e2s   = e2g[klane] * 2048.0f;

        f32x16 acc0, acc1;
        #pragma unroll
        for (int i = 0; i < 16; i++) { acc0[i] = 0.0f; acc1[i] = 0.0f; }

        #pragma unroll
        for (int s = 0; s < 4; s++) {   // pass hh
            acc0 = __builtin_amdgcn_mfma_f32_32x32x16_bf16(ah[0][s], bh[s], acc0, 0, 0, 0);
            acc1 = __builtin_amdgcn_mfma_f32_32x32x16_bf16(ah[1][s], bh[s], acc1, 0, 0, 0);
        }
        #pragma unroll
        for (int s = 0; s < 4; s++) {   // pass hl
            acc0 = __builtin_amdgcn_mfma_f32_32x32x16_bf16(ah[0][s], bl[s], acc0, 0, 0, 0);
            acc1 = __builtin_amdgcn_mfma_f32_32x32x16_bf16(ah[1][s], bl[s], acc1, 0, 0, 0);
        }
        #pragma unroll
        for (int s = 0; s < 4; s++) {   // pass lh
            acc0 = __builtin_amdgcn_mfma_f32_32x32x16_bf16(al[0][s], bh[s], acc0, 0, 0, 0);
            acc1 = __builtin_amdgcn_mfma_f32_32x32x16_bf16(al[1][s], bh[s], acc1, 0, 0, 0);
        }

        #pragma unroll
        for (int r = 0; r < 16; r++) {
            int q0   = (int)fmaf(acc0[r], -4096.0f, e2s);     // 2048*(e2-2dot), trunc
            int key0 = (int)(((unsigned)q0) << 10) | klane;
            int lo0 = min(b1[0][r], key0), hi0 = max(b1[0][r], key0);
            b1[0][r] = lo0; b2[0][r] = min(b2[0][r], hi0);

            int q1   = (int)fmaf(acc1[r], -4096.0f, e2s);
            int key1 = (int)(((unsigned)q1) << 10) | klane;
            int lo1 = min(b1[1][r], key1), hi1 = max(b1[1][r], key1);
            b1[1][r] = lo1; b2[1][r] = min(b2[1][r], hi1);
        }
    }

    // ---- cross-lane reduction (per half-wave = 32 lanes sharing a row) ----
    int sm1 = 0x7FFFFFFF, sm2 = 0x7FFFFFFF, sc = 1;
    unsigned long long hm = (lane < 32) ? 0xFFFFFFFFull : 0xFFFFFFFF00000000ull;
    #pragma unroll
    for (int mt = 0; mt < 2; mt++) {
        #pragma unroll
        for (int r = 0; r < 16; r++) {
            int v1 = b1[mt][r], v2 = b2[mt][r];
            #pragma unroll
            for (int m = 1; m <= 16; m <<= 1) {
                int o1 = __shfl_xor(v1, m, 64);
                int o2 = __shfl_xor(v2, m, 64);
                int lo = min(v1, o1), hi = max(v1, o1);
                v1 = lo;
                v2 = min(min(v2, o2), hi);
            }
            int thr = (v1 >> 10) + 41;   // window = 41/2048 ~= 0.02
            bool in1 = (b1[mt][r] >> 10) <= thr;
            bool in2 = (b2[mt][r] >> 10) <= thr;
            unsigned long long B1 = __ballot(in1), B2 = __ballot(in2);
            int cnt = (int)__popcll(B1 & hm) + (int)__popcll(B2 & hm);
            int w1a = __shfl(v1, 0, 64),  w2a = __shfl(v2, 0, 64),  ca = __shfl(cnt, 0, 64);
            int w1b = __shfl(v1, 32, 64), w2b = __shfl(v2, 32, 64), cb = __shfl(cnt, 32, 64);
            int r0 = mt * 32 + (r & 3) + 8 * (r >> 2);
            if (lane == r0)     { sm1 = w1a; sm2 = w2a; sc = ca; }
            if (lane == r0 + 4) { sm1 = w1b; sm2 = w2b; sc = cb; }
        }
    }

    // ---- per-lane epilogue: lane owns row wbase+lane ----
    const int row = wbase + lane;
    int kw = sm1 & 1023;

    // ---- wave-cooperative exact full scan for sc>=3 rows (rare path).
    // All 64 lanes split the codebook (16 codes/lane) -> ~64x less serial depth
    // than a per-lane 1024-iteration scan.
    {
        unsigned long long fm = __ballot(sc >= 3);
        while (fm) {
            int j = __ffsll(fm) - 1; fm &= (fm - 1);
            const float4* xr = (const float4*)(x + (size_t)(wbase + j) * DIMV);
            float4 xb[16];
            float xb2 = 0.f;
            #pragma unroll
            for (int i = 0; i < 16; i++) {
                float4 v = xr[i];                 // broadcast load (same addr all lanes)
                xb[i] = v;
                xb2 += v.x * v.x + v.y * v.y + v.z * v.z + v.w * v.w;
            }
            float bd = 3.4e38f; int bc = 0;
            for (int t = 0; t < 16; t++) {
                int c = lane + (t << 6);
                const float4* ep = (const float4*)(et + (c << 6));
                float ax = 0.f, ay = 0.f, az = 0.f, aw = 0.f;
                #pragma unroll 4
                for (int i = 0; i < 16; i++) {
                    float4 ev = ep[i];
                    ax = fmaf(xb[i].x, ev.x, ax);
                    ay = fmaf(xb[i].y, ev.y, ay);
                    az = fmaf(xb[i].z, ev.z, az);
                    aw = fmaf(xb[i].w, ev.w, aw);
                }
                float dot = (ax + ay) + (az + aw);
                float d = (xb2 - 2.0f * dot) + e2g[c];
                if (d < bd) { bd = d; bc = c; }   // ascending c: lowest idx on ties
            }
            #pragma unroll
            for (int m = 1; m < 64; m <<= 1) {    // lexicographic (dist, idx) min
                float od = __shfl_xor(bd, m, 64);
                int   oc = __shfl_xor(bc, m, 64);
                if (od < bd || (od == bd && oc < bc)) { bd = od; bc = oc; }
            }
            if (lane == j) kw = bc;
        }
    }

    float4 xv[16];
    {
        const float4* xp = (const float4*)(x + (size_t)row * DIMV);
        #pragma unroll
        for (int i = 0; i < 16; i++) xv[i] = xp[i];
    }

    if (sc == 2) {
        // exact recheck of the two candidates
        float x2 = 0.f;
        #pragma unroll
        for (int i = 0; i < 16; i++)
            x2 += xv[i].x * xv[i].x + xv[i].y * xv[i].y + xv[i].z * xv[i].z + xv[i].w * xv[i].w;

        auto fdist = [&](int k) -> float {
            const float4* ep = (const float4*)(et + (k << 6));
            float ax = 0.f, ay = 0.f, az = 0.f, aw = 0.f;
            #pragma unroll
            for (int i = 0; i < 16; i++) {
                float4 ev = ep[i];
                ax = fmaf(xv[i].x, ev.x, ax);
                ay = fmaf(xv[i].y, ev.y, ay);
                az = fmaf(xv[i].z, ev.z, az);
                aw = fmaf(xv[i].w, ev.w, aw);
            }
            float dot = (ax + ay) + (az + aw);
            return (x2 - 2.0f * dot) + e2g[k];
        };

        int k2 = sm2 & 1023;
        float d1 = fdist(kw);
        float d2 = fdist(k2);
        if (d2 < d1 || (d2 == d1 && k2 < kw)) kw = k2;
    }

    const bool valid = (mask[row] == 0);   // valid = ~mask
    float sq = 0.f;
    float4* qp = (float4*)(out + OQ + (size_t)row * DIMV);
    const float4* erow = (const float4*)(et + (kw << 6));
    #pragma unroll
    for (int i = 0; i < 16; i++) {
        float4 xvv = xv[i];
        float4 ev  = erow[i];
        float q0 = xvv.x + (ev.x - xvv.x);
        float q1 = xvv.y + (ev.y - xvv.y);
        float q2 = xvv.z + (ev.z - xvv.z);
        float q3 = xvv.w + (ev.w - xvv.w);
        float4 q4 = {q0, q1, q2, q3};
        qp[i] = q4;
        float d0 = q0 - xvv.x, d1 = q1 - xvv.y, d2 = q2 - xvv.z, d3 = q3 - xvv.w;
        sq += d0 * d0 + d1 * d1 + d2 * d2 + d3 * d3;
    }

    // per-row code record: ONE plain coalesced 2B store, no atomics.
    kwv[row] = valid ? (unsigned short)kw : (unsigned short)0xFFFF;

    float v = valid ? sq : 0.0f;
    #pragma unroll
    for (int off = 32; off > 0; off >>= 1) v += __shfl_down(v, off, 64);
    if (lane == 0) atomicAdd(lossacc, v);
}

// ---------------------------------------------------------------- pass 2: per-code gather-sum
// Block c owns code c. Round-2's wave-per-code version was a skew straggler:
// the hottest code (~6K rows) did 6K SERIAL dependent loads in one wave (1021 us
// at 1.1% VALUBusy). Here: chunked scan -> LDS row queue -> all 4 waves split the
// queue and gather with 8 independent loads in flight. Serial depth /32.
__global__ __launch_bounds__(256) void vq_gather(
    const float* __restrict__ x, const unsigned short* __restrict__ kwv,
    float* __restrict__ esum, float* __restrict__ counts)
{
    const int tid  = threadIdx.x;
    const int lane = tid & 63;
    const int wid  = tid >> 6;
    const int c    = blockIdx.x;

    __shared__ unsigned short q[GCHUNK];   // row offsets within chunk (32 KB)
    __shared__ int   qn;
    __shared__ float part[4][64];

    const short8* kp = (const short8*)kwv;
    float acc = 0.f;
    int   cnt = 0;

    for (int cb = 0; cb < NROWS; cb += GCHUNK) {
        if (tid == 0) qn = 0;
        __syncthreads();

        // ---- scan this chunk: 2048 short8 / 256 threads = 8 coalesced 16B loads,
        // issued back-to-back for ILP, then tested.
        short8 vv[8];
        #pragma unroll
        for (int it = 0; it < 8; it++)
            vv[it] = kp[(cb >> 3) + it * 256 + tid];
        #pragma unroll
        for (int it = 0; it < 8; it++) {
            int rbase = cb + (it * 256 + tid) * 8;
            #pragma unroll
            for (int j = 0; j < 8; j++) {
                if ((unsigned short)vv[it][j] == (unsigned short)c) {
                    int p = atomicAdd(&qn, 1);
                    q[p] = (unsigned short)(rbase + j - cb);
                }
            }
        }
        __syncthreads();
        int n = qn;
        cnt += n;

        // ---- gather: wave w takes 8-entry batches at stride 32; 8 loads in flight.
        for (int i = wid * 8; i < n; i += 32) {
            int e = min(i + 8, n);
            float tmp[8];
            #pragma unroll
            for (int b = 0; b < 8; b++) {
                if (i + b < e) {
                    int row = cb + (int)q[i + b];
                    tmp[b] = x[(size_t)row * DIMV + lane];  // coalesced 256B per row
                } else {
                    tmp[b] = 0.f;
                }
            }
            acc += ((tmp[0] + tmp[1]) + (tmp[2] + tmp[3]))
                 + ((tmp[4] + tmp[5]) + (tmp[6] + tmp[7]));
        }
        __syncthreads();   // protect q/qn from next chunk until all waves done
    }

    part[wid][lane] = acc;
    __syncthreads();
    if (tid < 64) {
        float s = (part[0][lane] + part[1][lane]) + (part[2][lane] + part[3][lane]);
        esum[(c << 6) + lane] = s;
    }
    if (tid == 0) counts[c] = (float)cnt;
}

// ---------------------------------------------------------------- finalize A
__global__ __launch_bounds__(1024) void vq_finalA(
    const float* __restrict__ cluster_size, const float* __restrict__ counts,
    const float* __restrict__ lossacc, float* __restrict__ out,
    float* __restrict__ total_ws)
{
    __shared__ float s1[1024];
    __shared__ float s2[1024];
    int k = threadIdx.x;
    float c   = counts[k];
    float ncs = cluster_size[k] * DECAYF + OMDF * c;
    out[ONC + k] = ncs;
    s1[k] = ncs; s2[k] = c;
    __syncthreads();
    for (int off = 512; off > 0; off >>= 1) {
        if (k < off) { s1[k] += s1[k + off]; s2[k] += s2[k + off]; }
        __syncthreads();
    }
    if (k == 0) {
        total_ws[0] = s1[0];
        out[OL] = lossacc[0] / (s2[0] * (float)DIMV);
    }
}

// ---------------------------------------------------------------- finalize B (esum is k-major)
__global__ void vq_finalB(const float* __restrict__ embed_avg,
                          const float* __restrict__ esum,
                          float* __restrict__ out,
                          const float* __restrict__ total_ws)
{
    int idx = blockIdx.x * 256 + threadIdx.x;  // < 65536, idx = d*1024 + k
    int k = idx & (NEMB - 1);
    int d = idx >> 10;
    float avg = embed_avg[idx] * DECAYF + OMDF * esum[(k << 6) + d];
    out[OA + idx] = avg;
    float ncs   = out[ONC + k];
    float total = *total_ws;
    float sm = (ncs + EPSF) / (total + (float)NEMB * EPSF) * total;
    out[OE + idx] = avg / sm;
}

// ---------------------------------------------------------------- launcher
extern "C" void kernel_launch(void* const* d_in, const int* in_sizes, int n_in,
                              void* d_out, int out_size, void* d_ws, size_t ws_size,
                              hipStream_t stream)
{
    const float* x            = (const float*)d_in[0];
    const int*   mask         = (const int*)d_in[1];
    const float* embed        = (const float*)d_in[2];
    const float* cluster_size = (const float*)d_in[3];
    const float* embed_avg    = (const float*)d_in[4];
    float* out = (float*)d_out;
    float* ws  = (float*)d_ws;

    unsigned short* eh  = (unsigned short*)(out + OEH);
    unsigned short* el  = (unsigned short*)(out + OEL);
    unsigned short* kwv = (unsigned short*)(ws + WS_KWV);

    // zero loss + total only (esum/counts are plain-stored by vq_gather)
    hipMemsetAsync(ws + WS_LOSS, 0, 2 * sizeof(float), stream);

    vq_prep<<<65536 / 256, 256, 0, stream>>>(embed, ws + WS_ET);
    vq_e2<<<NEMB / 256, 256, 0, stream>>>(ws + WS_ET, ws + WS_E2);
    vq_prep_b<<<65536 / 256, 256, 0, stream>>>(embed, eh, el);
    vq_main<<<NROWS / 256, 256, 0, stream>>>(x, mask, eh, el, ws + WS_ET, ws + WS_E2,
                                             out, kwv, ws + WS_LOSS);
    vq_gather<<<NEMB, 256, 0, stream>>>(x, kwv, ws + WS_ESUM, ws + WS_CNT);
    vq_finalA<<<1, 1024, 0, stream>>>(cluster_size, ws + WS_CNT, ws + WS_LOSS,
                                      out, ws + WS_TOTAL);
    vq_finalB<<<65536 / 256, 256, 0, stream>>>(embed_avg, ws + WS_ESUM, out, ws + WS_TOTAL);
}